// Round 4
// baseline (201.371 us; speedup 1.0000x reference)
//
#include <hip/hip_runtime.h>

// ---------------------------------------------------------------------------
// Causal single-head attention, B=64 T=512 C=768 H=72, fp32 in/out.
// cast_w: W -> wbt bf16 [3][80][768] (transposed, padded, Wq pre-scaled)
// proj:   fused QKV GEMM (M=64, grid 512, 2 blocks/CU); Qg/Kg [32768][104]
//         bf16 (cols 72..103 zero), Vt [64][80][512] bf16 (row 72 = ones)
// attn:   flash-style, no running max, TK=128 KV tiles, denominator =
//         PV ones-column, XOR-swizzled lv, balanced 512-block grid.
// ---------------------------------------------------------------------------

typedef short bf16x8 __attribute__((ext_vector_type(8)));
typedef float f32x4 __attribute__((ext_vector_type(4)));

#define DEVI __device__ __forceinline__

DEVI unsigned f2bf(float f) {  // fp32 -> bf16 RNE (low 16 of result)
  unsigned u = __builtin_bit_cast(unsigned, f);
  return (u + 0x7fffu + ((u >> 16) & 1u)) >> 16;
}
DEVI unsigned pk2(float a, float b) { return f2bf(a) | (f2bf(b) << 16); }

DEVI void async16(void* lds, const void* g) {  // global->LDS, lane*16B
  __builtin_amdgcn_global_load_lds(
      (const __attribute__((address_space(1))) unsigned int*)g,
      (__attribute__((address_space(3))) unsigned int*)lds, 16, 0, 0);
}

// ---------------------------------------------------------------- cast_w ----
__global__ __launch_bounds__(256) void cast_w_k(const float* __restrict__ Wk,
                                                const float* __restrict__ Wq,
                                                const float* __restrict__ Wv,
                                                unsigned short* __restrict__ wbt) {
  __shared__ float ldsT[72][65];
  const int mat = blockIdx.x / 12, kc = blockIdx.x % 12;
  const float* W = (mat == 0) ? Wk : (mat == 1) ? Wq : Wv;
  const float sc = (mat == 1) ? 0.11785113019775793f : 1.0f;  // 72^-0.5 in q
  const float* src = W + kc * 64 * 72;
  for (int i = threadIdx.x; i < 1152; i += 256) {
    float4 d = *(const float4*)(src + i * 4);
    int e = i * 4;
    ldsT[e % 72][e / 72] = d.x;
    ldsT[(e + 1) % 72][(e + 1) / 72] = d.y;
    ldsT[(e + 2) % 72][(e + 2) / 72] = d.z;
    ldsT[(e + 3) % 72][(e + 3) / 72] = d.w;
  }
  __syncthreads();
  for (int c = threadIdx.x; c < 640; c += 256) {
    int h = c >> 3, kb = (c & 7) * 8;
    uint4 o = {0u, 0u, 0u, 0u};
    if (h < 72) {
      const float* rowp = &ldsT[h][kb];
      o.x = pk2(rowp[0] * sc, rowp[1] * sc);
      o.y = pk2(rowp[2] * sc, rowp[3] * sc);
      o.z = pk2(rowp[4] * sc, rowp[5] * sc);
      o.w = pk2(rowp[6] * sc, rowp[7] * sc);
    }
    *(uint4*)(wbt + ((size_t)mat * 80 + h) * 768 + kc * 64 + kb) = o;
  }
}

// ------------------------------------------------------------------ proj ----
// grid 512, 256 thr / 4 waves, 2 blocks/CU. M=64, N=240 (K|Q|V), BK=64.
// Wave: 16 rows x 240 cols = 15 tiles.
struct ProjSmem {
  union {
    struct { short x[64 * 64]; short w[240 * 64]; } s;  // 8 KB + 30 KB
    short t[80 * 72];                                   // V-transpose
  };
};

__global__ __launch_bounds__(256, 2) void proj_k(
    const float* __restrict__ x, const unsigned short* __restrict__ wbt,
    unsigned short* __restrict__ Kg, unsigned short* __restrict__ Qg,
    unsigned short* __restrict__ Vt) {
  __shared__ __align__(16) ProjSmem sm;
  const int row0 = blockIdx.x * 64;
  const int tid = threadIdx.x, wave = tid >> 6, lane = tid & 63;
  const int quad = lane >> 4, l16 = lane & 15;
  const int lrow = lane >> 3, lcb = lane & 7;

  f32x4 acc[15] = {};

  for (int k0 = 0; k0 < 768; k0 += 64) {
    // W tile [240][64], async16, source col-block swizzled
#pragma unroll
    for (int i = 0; i < 8; ++i) {
      int inst = i * 4 + wave;
      if (inst < 30) {
        int r = inst * 8 + lrow;
        async16(&sm.s.w[inst * 512], wbt + (size_t)r * 768 + k0 + (lcb ^ lrow) * 8);
      }
    }
    // x tile [64][64]: fp32 load -> bf16 -> swizzled ds_write_b128
#pragma unroll
    for (int i = 0; i < 2; ++i) {
      int task = tid + 256 * i;  // 512 = 64 rows x 8 col-blocks
      int row = task >> 3, cb = task & 7;
      const float* g = x + (size_t)(row0 + row) * 768 + k0 + cb * 8;
      float4 a = *(const float4*)g;
      float4 c = *(const float4*)(g + 4);
      uint4 o = {pk2(a.x, a.y), pk2(a.z, a.w), pk2(c.x, c.y), pk2(c.z, c.w)};
      *(uint4*)&sm.s.x[row * 64 + ((cb ^ (row & 7)) * 8)] = o;
    }
    __syncthreads();
#pragma unroll
    for (int ks = 0; ks < 2; ++ks) {
      const int pblk = ((ks << 2) | quad) ^ (l16 & 7);
      bf16x8 af = *(const bf16x8*)&sm.s.x[(wave * 16 + l16) * 64 + pblk * 8];
#pragma unroll
      for (int nt = 0; nt < 15; ++nt) {
        bf16x8 bf = *(const bf16x8*)&sm.s.w[(nt * 16 + l16) * 64 + pblk * 8];
        acc[nt] = __builtin_amdgcn_mfma_f32_16x16x32_bf16(af, bf, acc[nt], 0, 0, 0);
      }
    }
    __syncthreads();
  }

  // K (nt 0..4) / Q (nt 5..9): rows of 104, cols 72..103 zero.
#pragma unroll
  for (int gsel = 0; gsel < 2; ++gsel) {
    unsigned short* G = gsel ? Qg : Kg;
#pragma unroll
    for (int r = 0; r < 4; ++r) {
      size_t row = (size_t)row0 + wave * 16 + quad * 4 + r;
      unsigned short* p = G + row * 104;
#pragma unroll
      for (int nt = 0; nt < 5; ++nt)
        p[nt * 16 + l16] = (unsigned short)f2bf(acc[gsel * 5 + nt][r]);
      p[80 + l16] = 0;
      if (l16 < 8) p[96 + l16] = 0;
    }
  }
  // V (nt 10..14): transpose via LDS -> Vt [b][80][512], row 72 := ones.
#pragma unroll
  for (int nt = 0; nt < 5; ++nt)
#pragma unroll
    for (int r = 0; r < 4; ++r)
      sm.t[(nt * 16 + l16) * 72 + wave * 16 + quad * 4 + r] =
          (short)f2bf(acc[10 + nt][r]);
  __syncthreads();
  int b = blockIdx.x >> 3, t0 = (blockIdx.x & 7) * 64;
  const uint4 ones = {0x3F803F80u, 0x3F803F80u, 0x3F803F80u, 0x3F803F80u};
  for (int c = tid; c < 640; c += 256) {
    int hr = c >> 3, tc = (c & 7) * 8;
    uint4 d = *(const uint4*)&sm.t[hr * 72 + tc];
    if (hr == 72) d = ones;
    *(uint4*)(Vt + ((size_t)b * 80 + hr) * 512 + t0 + tc) = d;
  }
}

// ------------------------------------------------------------------ attn ----
// 512 blocks (balance-permuted (b,qb)), 4 waves, 16 Q-rows/wave, TK=128.
__global__ __launch_bounds__(256, 2) void attn_k(
    const unsigned short* __restrict__ Qg, const unsigned short* __restrict__ Kg,
    const unsigned short* __restrict__ Vt, float* __restrict__ out) {
  __shared__ __align__(16) short lk[128 * 104];    // 26.6 KB, stride 104 (2-way free)
  __shared__ __align__(16) short lv[80 * 128];     // 20.5 KB, 16-block XOR swizzle
  __shared__ __align__(16) short lp[4][16 * 136];  // 17.4 KB, per-wave P

  int idx = (blockIdx.x < 256) ? blockIdx.x : 767 - blockIdx.x;
  const int qb = 7 - (idx >> 6), b = idx & 63;
  const int tid = threadIdx.x, wave = tid >> 6, lane = tid & 63;
  const int quad = lane >> 4, l16 = lane & 15;
  const int trow0 = qb * 64 + wave * 16;

  bf16x8 qf[3];
#pragma unroll
  for (int kt = 0; kt < 3; ++kt)
    qf[kt] = *(const bf16x8*)(Qg + ((size_t)b * 512 + trow0 + l16) * 104 + kt * 32 + quad * 8);

  f32x4 o[5] = {};

  const int nkb = (qb >> 1) + 1;
  for (int kb = 0; kb < nkb; ++kb) {
    const int s0 = kb * 128;
    const bool diag = (kb == (qb >> 1));
    const int nact = diag ? ((qb & 1) * 4 + wave + 1) : 8;   // live S tiles
    const int kslim = diag ? ((nact + 1) >> 1) : 4;          // live PV K-steps
    const int nKinst = (diag && !(qb & 1)) ? 13 : 26;        // K rows needed

    // K tile: linear copy, 1024 B per wave-inst
#pragma unroll
    for (int j = 0; j < 7; ++j) {
      int inst = j * 4 + wave;
      if (inst < nKinst)
        async16(&lk[inst * 512], Kg + ((size_t)b * 512 + s0) * 104 + inst * 512 + lane * 8);
    }
    // V^T tile [80][128], 4 rows per inst, source col-block swizzled
#pragma unroll
    for (int j = 0; j < 5; ++j) {
      int inst = j * 4 + wave;
      int r = inst * 4 + (lane >> 4);
      int cb = lane & 15;
      async16(&lv[inst * 512],
              Vt + ((size_t)b * 80 + r) * 512 + s0 + ((cb ^ (r & 15)) * 8));
    }
    __syncthreads();

    // S = Q K^T over live tiles
    f32x4 sacc[8] = {};
#pragma unroll
    for (int kt = 0; kt < 3; ++kt)
#pragma unroll
      for (int nt = 0; nt < 8; ++nt)
        if (nt < nact) {
          bf16x8 kf = *(const bf16x8*)&lk[(nt * 16 + l16) * 104 + kt * 32 + quad * 8];
          sacc[nt] = __builtin_amdgcn_mfma_f32_16x16x32_bf16(qf[kt], kf, sacc[nt], 0, 0, 0);
        }
    if (diag) {  // per-element mask on the straddling tile
#pragma unroll
      for (int nt = 0; nt < 8; ++nt)
        if (nt == nact - 1)
#pragma unroll
          for (int r = 0; r < 4; ++r) {
            int t = trow0 + quad * 4 + r;
            if (s0 + nt * 16 + l16 > t) sacc[nt][r] = -1e30f;
          }
    }
    // p = exp(s), write A-layout into per-wave LDS (zeros beyond nact)
#pragma unroll
    for (int nt = 0; nt < 8; ++nt)
#pragma unroll
      for (int r = 0; r < 4; ++r) {
        float p = (nt < nact) ? __expf(sacc[nt][r]) : 0.0f;
        lp[wave][(quad * 4 + r) * 136 + nt * 16 + l16] = (short)f2bf(p);
      }
    // O += P V^  (col 72 of V^ is ones -> denominator in o[4])
#pragma unroll
    for (int ks = 0; ks < 4; ++ks)
      if (ks < kslim) {
        bf16x8 pf = *(const bf16x8*)&lp[wave][l16 * 136 + ks * 32 + quad * 8];
#pragma unroll
        for (int nt = 0; nt < 5; ++nt) {
          bf16x8 vf = *(const bf16x8*)&lv[(nt * 16 + l16) * 128 + (((ks << 2) | quad) ^ l16) * 8];
          o[nt] = __builtin_amdgcn_mfma_f32_16x16x32_bf16(pf, vf, o[nt], 0, 0, 0);
        }
      }
    __syncthreads();
  }

#pragma unroll
  for (int r = 0; r < 4; ++r) {
    float l = __shfl(o[4][r], (lane & 48) | 8, 64);
    float inv = 1.0f / l;
    size_t t = (size_t)b * 512 + trow0 + quad * 4 + r;
#pragma unroll
    for (int nt = 0; nt < 5; ++nt) {
      int h = nt * 16 + l16;
      if (h < 72) out[t * 72 + h] = o[nt][r] * inv;
    }
  }
}

// ---------------------------------------------------------------------------
extern "C" void kernel_launch(void* const* d_in, const int* in_sizes, int n_in,
                              void* d_out, int out_size, void* d_ws, size_t ws_size,
                              hipStream_t stream) {
  const float* x  = (const float*)d_in[0];
  const float* Wk = (const float*)d_in[1];
  const float* Wq = (const float*)d_in[2];
  const float* Wv = (const float*)d_in[3];
  float* out = (float*)d_out;

  char* ws = (char*)d_ws;
  unsigned short* Kg  = (unsigned short*)(ws);             // 6,815,744
  unsigned short* Qg  = (unsigned short*)(ws + 6815744);   // 6,815,744
  unsigned short* Vt  = (unsigned short*)(ws + 13631488);  // 5,242,880
  unsigned short* wbt = (unsigned short*)(ws + 18874368);  //   368,640

  cast_w_k<<<36, 256, 0, stream>>>(Wk, Wq, Wv, wbt);
  proj_k<<<512, 256, 0, stream>>>(x, wbt, Kg, Qg, Vt);
  attn_k<<<512, 256, 0, stream>>>(Qg, Kg, Vt, out);
}